// Round 4
// baseline (561.556 us; speedup 1.0000x reference)
//
#include <hip/hip_runtime.h>

typedef short short8 __attribute__((ext_vector_type(8)));
typedef float f32x16 __attribute__((ext_vector_type(16)));

// Problem constants
#define DIMV   64
#define NEMB   1024
#define NROWS  262144          // B*T = 2048*128
#define DECAYF 0.99f
#define OMDF   0.01f
#define EPSF   1e-5f
#define GCHUNK 16384           // rows per gather chunk (fallback scan path)

// d_out layout (floats): quantize | loss | new_embed | new_cluster_size | new_embed_avg
#define OQ   0
#define OL   16777216
#define OE   16777217
#define ONC  16842753
#define OA   16843777
// EH/EL (bf16 split codebook, MFMA-B-fragment order) live in the d_out tail:
// written by vq_prep_b, read by vq_main, then overwritten by finalA/finalB.
#define OEH  16777216
#define OEL  (16777216 + 32768)

// d_ws layout (floats)
#define WS_E2     0        // 1024: ||e_k||^2
#define WS_CNT    1024     // 1024: counts (plain stores from vq_off / fallback gather)
#define WS_ESUM   2048     // 65536: embed_sum, K-MAJOR: [k][d]
#define WS_LOSS   67584    // 1
#define WS_TOTAL  67585    // 1
#define WS_ET     67588    // 65536: embed transposed [k][d] fp32
#define WS_KWV    133124   // 131072 floats = 262144 ushorts: per-row code (0xFFFF = masked)
#define WS_RNK    264196   // 65536 floats = 262144 uchars: rank of row within its block's code
#define WS_BASE   329732   // 1024 ints: exclusive prefix of counts over codes
#define WS_SORT   330756   // 262144 ints: row ids sorted by code
#define WS_HIST   592900   // 1024*1024 ints: per-(block,code) histogram -> exclusive prefix
#define WS_END    1641476  // floats needed for the sort path

// RNE float->bf16 (no NaN in data), and back
__device__ __forceinline__ unsigned short f2bf(float f) {
    unsigned u = __float_as_uint(f);
    u = u + 0x7FFFu + ((u >> 16) & 1u);
    return (unsigned short)(u >> 16);
}
__device__ __forceinline__ float bf2f(unsigned short h) {
    return __uint_as_float(((unsigned)h) << 16);
}

// ---------------------------------------------------------------- prep: transpose embed -> et[k][d]
__global__ void vq_prep(const float* __restrict__ embed, float* __restrict__ et)
{
    int idx = blockIdx.x * 256 + threadIdx.x;   // < 65536, idx = d*1024 + k
    int d = idx >> 10;
    int k = idx & (NEMB - 1);
    et[k * DIMV + d] = embed[idx];
}

__global__ void vq_e2(const float* __restrict__ et, float* __restrict__ e2)
{
    int k = blockIdx.x * 256 + threadIdx.x;   // k < 1024
    const float4* ep = (const float4*)(et + k * DIMV);
    float s = 0.f;
    #pragma unroll
    for (int i = 0; i < 16; i++) {
        float4 v = ep[i];
        s = fmaf(v.x, v.x, fmaf(v.y, v.y, fmaf(v.z, v.z, fmaf(v.w, v.w, s))));
    }
    e2[k] = s;
}

// ---------------------------------------------------------------- prep: split codebook into bf16 hi/lo,
// pre-swizzled into 32x32x16 MFMA B-fragment order:
// frag(nt,s): lane L, elem j  <->  B[k = s*16 + (L>>5)*8 + j][n = nt*32 + (L&31)]
__global__ void vq_prep_b(const float* __restrict__ embed,
                          unsigned short* __restrict__ eh,
                          unsigned short* __restrict__ el)
{
    int t = blockIdx.x * 256 + threadIdx.x;    // 0..65535
    int j  = t & 7;
    int L  = (t >> 3) & 63;
    int s  = (t >> 9) & 3;
    int nt = t >> 11;                          // 0..31
    int d    = s * 16 + (L >> 5) * 8 + j;
    int code = nt * 32 + (L & 31);
    float e = embed[d * NEMB + code];
    unsigned short hb = f2bf(e);
    eh[t] = hb;
    el[t] = f2bf(e - bf2f(hb));
}

// ---------------------------------------------------------------- main
// No global atomics except ONE per-wave loss add. Emits per-row code (kwv),
// per-row rank within block (rnkb) and per-block histogram (hist) for the
// counting-sort EMA pipeline — all plain stores / LDS-local atomics.
__global__ __launch_bounds__(256, 2) void vq_main(
    const float* __restrict__ x, const int* __restrict__ mask,
    const unsigned short* __restrict__ eh, const unsigned short* __restrict__ el,
    const float* __restrict__ et, const float* __restrict__ e2g,
    float* __restrict__ out, unsigned short* __restrict__ kwv,
    float* __restrict__ lossacc,
    unsigned char* __restrict__ rnkb, int* __restrict__ hist)
{
    const int tid  = threadIdx.x;
    const int lane = tid & 63;
    const int wid  = tid >> 6;
    const int wbase = blockIdx.x * 256 + wid * 64;   // wave's first row
    const int lm = lane & 31;    // m (A) / n (B) within tile
    const int lh = lane >> 5;    // k-half selector

    __shared__ int hcur[NEMB];   // 4 KB histogram cursor
    if (hist) {
        for (int i = tid; i < NEMB; i += 256) hcur[i] = 0;
        __syncthreads();
    }

    // ---- A fragments: xh/xl for 2 M-tiles x 4 K-steps. A[m=lane&31][k=(lane>>5)*8+j]
    short8 ah[2][4], al[2][4];
    #pragma unroll
    for (int mt = 0; mt < 2; mt++) {
        const float* xr = x + (size_t)(wbase + mt * 32 + lm) * DIMV + lh * 8;
        #pragma unroll
        for (int s = 0; s < 4; s++) {
            const float* xp = xr + s * 16;
            #pragma unroll
            for (int j = 0; j < 8; j++) {
                float f = xp[j];
                unsigned short hb = f2bf(f);
                ah[mt][s][j] = (short)hb;
                al[mt][s][j] = (short)f2bf(f - bf2f(hb));
            }
        }
    }

    // per-lane top-2 keys per (mtile, acc-reg); key = (q<<10)|k, q = trunc(2048*(e2-2dot))
    int b1[2][16], b2[2][16];
    #pragma unroll
    for (int mt = 0; mt < 2; mt++)
        #pragma unroll
        for (int r = 0; r < 16; r++) { b1[mt][r] = 0x7FFFFFFF; b2[mt][r] = 0x7FFFFFFF; }

    const short8* ehf = (const short8*)eh;
    const short8* elf = (const short8*)el;

    for (int nt = 0; nt < 32; nt++) {
        short8 bh[4], bl[4];
        #pragma unroll
        for (int s = 0; s < 4; s++) {
            bh[s] = ehf[(nt * 4 + s) * 64 + lane];
            bl[s] = elf[(nt * 4 + s) * 64 + lane];
        }
        const int   klane = nt * 32 + lm;
        const float e2s   = e2g[klane] * 2048.0f;

        f32x16 acc0, acc1;
        #pragma unroll
        for (int i = 0; i < 16; i++) { acc0[i] = 0.0f; acc1[i] = 0.0f; }

        #pragma unroll
        for (int s = 0; s < 4; s++) {   // pass hh
            acc0 = __builtin_amdgcn_mfma_f32_32x32x16_bf16(ah[0][s], bh[s], acc0, 0, 0, 0);
            acc1 = __builtin_amdgcn_mfma_f32_32x32x16_bf16(ah[1][s], bh[s], acc1, 0, 0, 0);
        }
        #pragma unroll
        for (int s = 0; s < 4; s++) {   // pass hl
            acc0 = __builtin_amdgcn_mfma_f32_32x32x16_bf16(ah[0][s], bl[s], acc0, 0, 0, 0);
            acc1 = __builtin_amdgcn_mfma_f32_32x32x16_bf16(ah[1][s], bl[s], acc1, 0, 0, 0);
        }
        #pragma unroll
        for (int s = 0; s < 4; s++) {   // pass lh
            acc0 = __builtin_amdgcn_mfma_f32_32x32x16_bf16(al[0][s], bh[s], acc0, 0, 0, 0);
            acc1 = __builtin_amdgcn_mfma_f32_32x32x16_bf16(al[1][s], bh[s], acc1, 0, 0, 0);
        }

        #pragma unroll
        for (int r = 0; r < 16; r++) {
            int q0   = (int)fmaf(acc0[r], -4096.0f, e2s);     // 2048*(e2-2dot), trunc
            int key0 = (int)(((unsigned)q0) << 10) | klane;
            int lo0 = min(b1[0][r], key0), hi0 = max(b1[0][r], key0);
            b1[0][r] = lo0; b2[0][r] = min(b2[0][r], hi0);

            int q1   = (int)fmaf(acc1[r], -4096.0f, e2s);
            int key1 = (int)(((unsigned)q1) << 10) | klane;
            int lo1 = min(b1[1][r], key1), hi1 = max(b1[1][r], key1);
            b1[1][r] = lo1; b2[1][r] = min(b2[1][r], hi1);
        }
    }

    // ---- cross-lane reduction (per half-wave = 32 lanes sharing a row) ----
    int sm1 = 0x7FFFFFFF, sm2 = 0x7FFFFFFF, sc = 1;
    unsigned long long hm = (lane < 32) ? 0xFFFFFFFFull : 0xFFFFFFFF00000000ull;
    #pragma unroll
    for (int mt = 0; mt < 2; mt++) {
        #pragma unroll
        for (int r = 0; r < 16; r++) {
            int v1 = b1[mt][r], v2 = b2[mt][r];
            #pragma unroll
            for (int m = 1; m <= 16; m <<= 1) {
                int o1 = __shfl_xor(v1, m, 64);
                int o2 = __shfl_xor(v2, m, 64);
                int lo = min(v1, o1), hi = max(v1, o1);
                v1 = lo;
                v2 = min(min(v2, o2), hi);
            }
            int thr = (v1 >> 10) + 41;   // window = 41/2048 ~= 0.02
            bool in1 = (b1[mt][r] >> 10) <= thr;
            bool in2 = (b2[mt][r] >> 10) <= thr;
            unsigned long long B1 = __ballot(in1), B2 = __ballot(in2);
            int cnt = (int)__popcll(B1 & hm) + (int)__popcll(B2 & hm);
            int w1a = __shfl(v1, 0, 64),  w2a = __shfl(v2, 0, 64),  ca = __shfl(cnt, 0, 64);
            int w1b = __shfl(v1, 32, 64), w2b = __shfl(v2, 32, 64), cb = __shfl(cnt, 32, 64);
            int r0 = mt * 32 + (r & 3) + 8 * (r >> 2);
            if (lane == r0)     { sm1 = w1a; sm2 = w2a; sc = ca; }
            if (lane == r0 + 4) { sm1 = w1b; sm2 = w2b; sc = cb; }
        }
    }

    // ---- per-lane epilogue: lane owns row wbase+lane ----
    const int row = wbase + lane;
    int kw = sm1 & 1023;

    // ---- wave-cooperative exact full scan for sc>=3 rows (rare path).
    {
        unsigned long long fm = __ballot(sc >= 3);
        while (fm) {
            int j = __ffsll(fm) - 1; fm &= (fm - 1);
            const float4* xr = (const float4*)(x + (size_t)(wbase + j) * DIMV);
            float4 xb[16];
            float xb2 = 0.f;
            #pragma unroll
            for (int i = 0; i < 16; i++) {
                float4 v = xr[i];                 // broadcast load (same addr all lanes)
                xb[i] = v;
                xb2 += v.x * v.x + v.y * v.y + v.z * v.z + v.w * v.w;
            }
            float bd = 3.4e38f; int bc = 0;
            for (int t = 0; t < 16; t++) {
                int c = lane + (t << 6);
                const float4* ep = (const float4*)(et + (c << 6));
                float ax = 0.f, ay = 0.f, az = 0.f, aw = 0.f;
                #pragma unroll 4
                for (int i = 0; i < 16; i++) {
                    float4 ev = ep[i];
                    ax = fmaf(xb[i].x, ev.x, ax);
                    ay = fmaf(xb[i].y, ev.y, ay);
                    az = fmaf(xb[i].z, ev.z, az);
                    aw = fmaf(xb[i].w, ev.w, aw);
                }
                float dot = (ax + ay) + (az + aw);
                float d = (xb2 - 2.0f * dot) + e2g[c];
                if (d < bd) { bd = d; bc = c; }   // ascending c: lowest idx on ties
            }
            #pragma unroll
            for (int m = 1; m < 64; m <<= 1) {    // lexicographic (dist, idx) min
                float od = __shfl_xor(bd, m, 64);
                int   oc = __shfl_xor(bc, m, 64);
                if (od < bd || (od == bd && oc < bc)) { bd = od; bc = oc; }
            }
            if (lane == j) kw = bc;
        }
    }

    float4 xv[16];
    {
        const float4* xp = (const float4*)(x + (size_t)row * DIMV);
        #pragma unroll
        for (int i = 0; i < 16; i++) xv[i] = xp[i];
    }

    if (sc == 2) {
        // exact recheck of the two candidates
        float x2 = 0.f;
        #pragma unroll
        for (int i = 0; i < 16; i++)
            x2 += xv[i].x * xv[i].x + xv[i].y * xv[i].y + xv[i].z * xv[i].z + xv[i].w * xv[i].w;

        auto fdist = [&](int k) -> float {
            const float4* ep = (const float4*)(et + (k << 6));
            float ax = 0.f, ay = 0.f, az = 0.f, aw = 0.f;
            #pragma unroll
            for (int i = 0; i < 16; i++) {
                float4 ev = ep[i];
                ax = fmaf(xv[i].x, ev.x, ax);
                ay = fmaf(xv[i].y, ev.y, ay);
                az = fmaf(xv[i].z, ev.z, az);
                aw = fmaf(xv[i].w, ev.w, aw);
            }
            float dot = (ax + ay) + (az + aw);
            return (x2 - 2.0f * dot) + e2g[k];
        };

        int k2 = sm2 & 1023;
        float d1 = fdist(kw);
        float d2 = fdist(k2);
        if (d2 < d1 || (d2 == d1 && k2 < kw)) kw = k2;
    }

    const bool valid = (mask[row] == 0);   // valid = ~mask
    float sq = 0.f;
    float4* qp = (float4*)(out + OQ + (size_t)row * DIMV);
    const float4* erow = (const float4*)(et + (kw << 6));
    #pragma unroll
    for (int i = 0; i < 16; i++) {
        float4 xvv = xv[i];
        float4 ev  = erow[i];
        float q0 = xvv.x + (ev.x - xvv.x);
        float q1 = xvv.y + (ev.y - xvv.y);
        float q2 = xvv.z + (ev.z - xvv.z);
        float q3 = xvv.w + (ev.w - xvv.w);
        float4 q4 = {q0, q1, q2, q3};
        qp[i] = q4;
        float d0 = q0 - xvv.x, d1 = q1 - xvv.y, d2 = q2 - xvv.z, d3 = q3 - xvv.w;
        sq += d0 * d0 + d1 * d1 + d2 * d2 + d3 * d3;
    }

    // per-row code record: ONE plain coalesced 2B store, no atomics.
    kwv[row] = valid ? (unsigned short)kw : (unsigned short)0xFFFF;

    // ---- counting-sort bookkeeping: rank within block via LDS cursor,
    // per-block histogram via plain coalesced stores.
    if (hist) {
        int rk = 0;
        if (valid) rk = atomicAdd(&hcur[kw], 1);
        rnkb[row] = (unsigned char)rk;
        __syncthreads();
        for (int i = tid; i < NEMB; i += 256)
            hist[(size_t)blockIdx.x * NEMB + i] = hcur[i];
    }

    float v = valid ? sq : 0.0f;
    #pragma unroll
    for (int off = 32; off > 0; off >>= 1) v += __shfl_down(v, off, 64);
    if (lane == 0) atomicAdd(lossacc, v);
}

// ---------------------------------------------------------------- sort pass A: per-code exclusive
// prefix of hist along blocks (in place) + counts. Block handles 16 codes; thread b owns
// source-block b's row of the histogram (coalesced int4 read/write).
__global__ __launch_bounds__(1024) void vq_off(int* __restrict__ hist, float* __restrict__ cntf)
{
    const int b    = threadIdx.x;      // source vq_main block id, 0..1023
    const int lane = b & 63;
    const int wv   = b >> 6;           // 0..15
    const int c0   = blockIdx.x * 16;
    __shared__ int wsum[16];

    int hv[16];
    {
        const int4* hp = (const int4*)(hist + (size_t)b * NEMB + c0);
        int4 a0 = hp[0], a1 = hp[1], a2 = hp[2], a3 = hp[3];
        hv[0]=a0.x;  hv[1]=a0.y;  hv[2]=a0.z;  hv[3]=a0.w;
        hv[4]=a1.x;  hv[5]=a1.y;  hv[6]=a1.z;  hv[7]=a1.w;
        hv[8]=a2.x;  hv[9]=a2.y;  hv[10]=a2.z; hv[11]=a2.w;
        hv[12]=a3.x; hv[13]=a3.y; hv[14]=a3.z; hv[15]=a3.w;
    }

    int pre[16];
    #pragma unroll
    for (int j = 0; j < 16; j++) {
        int v = hv[j];
        int inc = v;
        #pragma unroll
        for (int off = 1; off < 64; off <<= 1) {
            int t = __shfl_up(inc, off, 64);
            if (lane >= off) inc += t;
        }
        if (lane == 63) wsum[wv] = inc;
        __syncthreads();
        int woff = 0;
        #pragma unroll
        for (int w = 0; w < 16; w++) if (w < wv) woff += wsum[w];
        if (b == 0) {
            int tot = 0;
            #pragma unroll
            for (int w = 0; w < 16; w++) tot += wsum[w];
            cntf[c0 + j] = (float)tot;
        }
        pre[j] = woff + inc - v;       // exclusive prefix over blocks for code c0+j
        __syncthreads();               // wsum reuse
    }

    {
        int4* op = (int4*)(hist + (size_t)b * NEMB + c0);
        op[0] = make_int4(pre[0],  pre[1],  pre[2],  pre[3]);
        op[1] = make_int4(pre[4],  pre[5],  pre[6],  pre[7]);
        op[2] = make_int4(pre[8],  pre[9],  pre[10], pre[11]);
        op[3] = make_int4(pre[12], pre[13], pre[14], pre[15]);
    }
}

// ---------------------------------------------------------------- sort pass B: base[c] = exclusive
// prefix of counts over codes. Single block, 1024 threads.
__global__ __launch_bounds__(1024) void vq_base(const float* __restrict__ cntf,
                                                int* __restrict__ base)
{
    const int c    = threadIdx.x;
    const int lane = c & 63;
    const int wv   = c >> 6;
    __shared__ int wsum[16];
    int v = (int)cntf[c];
    int inc = v;
    #pragma unroll
    for (int off = 1; off < 64; off <<= 1) {
        int t = __shfl_up(inc, off, 64);
        if (lane >= off) inc += t;
    }
    if (lane == 63) wsum[wv] = inc;
    __syncthreads();
    int woff = 0;
    #pragma unroll
    for (int w = 0; w < 16; w++) if (w < wv) woff += wsum[w];
    base[c] = woff + inc - v;
}

// ---------------------------------------------------------------- sort pass C: scatter row ids
__global__ void vq_scatter(const unsigned short* __restrict__ kwv,
                           const unsigned char* __restrict__ rnkb,
                           const int* __restrict__ hist, const int* __restrict__ base,
                           int* __restrict__ sorted)
{
    int row = blockIdx.x * 256 + threadIdx.x;
    unsigned short c = kwv[row];
    if (c != 0xFFFFu) {
        int dest = base[c] + hist[(size_t)blockIdx.x * NEMB + c] + (int)rnkb[row];
        sorted[dest] = row;
    }
}

// ---------------------------------------------------------------- sort pass D: gather-sum.
// Block per code; rows contiguous in sorted[]. 8 waves x 8-deep load ILP,
// fully-coalesced 256B row reads (d = lane). One plain store per (code,dim).
__global__ __launch_bounds__(512) void vq_gather2(
    const float* __restrict__ x, const int* __restrict__ sorted,
    const int* __restrict__ base, const float* __restrict__ cntf,
    float* __restrict__ esum)
{
    const int tid  = threadIdx.x;
    const int lane = tid & 63;
    const int wid  = tid >> 6;      // 0..7
    const int c    = blockIdx.x;
    const int n    = (int)cntf[c];
    const int b0   = base[c];
    __shared__ float part[8][64];

    float acc = 0.f;
    for (int i = wid * 8; i < n; i += 64) {
        float tmp[8];
        #pragma unroll
        for (int k = 0; k < 8; k++) {
            int idx = i + k;
            tmp[k] = 0.f;
            if (idx < n) {
                int row = sorted[b0 + idx];          // broadcast load
                tmp[k] = x[(size_t)row * DIMV + lane];
            }
        }
        acc += ((tmp[0] + tmp[1]) + (tmp[2] + tmp[3]))
             + ((tmp[4] + tmp[5]) + (tmp[6] + tmp[7]));
    }

    part[wid][lane] = acc;
    __syncthreads();
    if (tid < 64) {
        float s = 0.f;
        #pragma unroll
        for (int w = 0; w < 8; w++) s += part[w][lane];
        esum[(c << 6) + lane] = s;
    }
}

// ---------------------------------------------------------------- fallback: O(K*N) scan gather
// (used only if workspace is too small for the sort path)
__global__ __launch_bounds__(256) void vq_gather(
    const float* __restrict__ x, const unsigned short* __restrict__ kwv,
    float* __restrict__ esum, float* __restrict__ counts)
{
    const int tid  = threadIdx.x;
    const int lane = tid & 63;
    const int wid  = tid >> 6;
    const int c    = blockIdx.x;

    __shared__ unsigned short q[GCHUNK];
    __shared__ int   qn;
    __shared__ float part[4][64];

    const short8* kp = (const short8*)kwv;
    float acc = 0.f;
    int   cnt = 0;

    for (int cb = 0; cb < NROWS; cb += GCHUNK) {
        if (tid == 0) qn = 0;
        __syncthreads();

        short8 vv[8];
        #pragma unroll
        for (int it = 0; it < 8; it++)
            vv[it] = kp[(cb >> 3) + it * 256 + tid];
        #pragma unroll
        for (int it = 0; it < 8; it++) {
            int rbase = cb + (it * 256 + tid) * 8;
            #pragma unroll
            for (int j = 0; j < 8; j++) {
                if ((unsigned short)vv[it][j] == (unsigned short)c) {
                    int p = atomicAdd(&qn, 1);
                    q[p] = (unsigned short)(rbase + j - cb);
                }
            }
        }
        __syncthreads();
        int n = qn;
        cnt += n;

        for (int i = wid * 8; i < n; i += 32) {
            int e = min(i + 8, n);
            float tmp[8];
            #pragma unroll
            for (int b = 0; b < 8; b++) {
                if (i + b < e) {
                    int row = cb + (int)q[i + b];
                    tmp[b] = x[(size_t)row * DIMV + lane];
                } else {
                    tmp[b] = 0.f;
                }
            }
            acc += ((tmp[0] + tmp[1]) + (tmp[2] + tmp[3]))
                 + ((tmp[4] + tmp[5]) + (tmp[6] + tmp[7]));
        }
        __syncthreads();
    }

    part[wid][lane] = acc;
    __syncthreads();
    if (tid < 64) {
        float s = (part[0][lane] + part[1][lane]) + (part[2][lane] + part[3][lane]);
        esum[(c << 6) + lane] = s;
    }
    if (tid == 0) counts[c] = (float)cnt;
}

// ---------------------------------------------------------------- finalize A
__global__ __launch_bounds__(1024) void vq_finalA(
    const float* __restrict__ cluster_size, const float* __restrict__ counts,
    const float* __restrict__ lossacc, float* __restrict__ out,
    float* __restrict__ total_ws)
{
    __shared__ float s1[1024];
    __shared__ float s2[1024];
    int k = threadIdx.x;
    float c   = counts[k];
    float ncs = cluster_size[k] * DECAYF + OMDF * c;
    out[ONC + k] = ncs;
    s1[k] = ncs; s2[k] = c;
    __syncthreads();
    for (int off = 512; off > 0; off >>= 1) {
        if (k < off) { s1[k] += s1[k + off]; s2[k] += s2[k + off]; }
        __syncthreads();
    }
    if (k == 0) {
        total_ws[0] = s1[0];
        out[OL] = lossacc[0] / (s2[0] * (float)DIMV);
    }
}

// ---------------------------------------------------------------- finalize B (esum is k-major)
__global__ void vq_finalB(const float* __restrict__ embed_avg,
                          const float* __restrict__ esum,
                          float* __restrict__ out,
                          const float* __restrict__ total_ws)
{
    int idx = blockIdx.x * 256 + threadIdx.x;  // < 65536, idx = d*1024 + k
    int k = idx & (NEMB - 1);
    int d = idx >> 10;
    float avg = embed_avg[idx] * DECAYF + OMDF * esum[(k << 6) + d];
    out[OA + idx] = avg;
    float ncs   = out[ONC + k];
    float total = *total_ws;
    float sm = (ncs + EPSF) / (total + (float)NEMB * EPSF) * total;
    out[OE + idx] = avg / sm;
}

// ---------------------------------------------------------------- launcher
extern "C" void kernel_launch(void* const* d_in, const int* in_sizes, int n_in,
                              void* d_out, int out_size, void* d_ws, size_t ws_size,
                              hipStream_t stream)
{
    const float* x            = (const float*)d_in[0];
    const int*   mask         = (const int*)d_in[1];
    const float* embed        = (const float*)d_in[2];
    const float* cluster_size = (const float*)d_in[3];
    const float* embed_avg    = (const float*)d_in[4];
    float* out = (float*)d_out;
    float* ws  = (float*)d_ws;

    unsigned short* eh   = (unsigned short*)(out + OEH);
    unsigned short* el   = (unsigned short*)(out + OEL);
    unsigned short* kwv  = (unsigned short*)(ws + WS_KWV);
    unsigned char*  rnkb = (unsigned char*)(ws + WS_RNK);
    int*            base = (int*)(ws + WS_BASE);
    int*            sortd= (int*)(ws + WS_SORT);
    int*            hist = (int*)(ws + WS_HIST);

    const bool sort_ok = ws_size >= (size_t)WS_END * sizeof(float);

    // zero loss + total only (counts/esum are plain-stored downstream)
    hipMemsetAsync(ws + WS_LOSS, 0, 2 * sizeof(float), stream);

    vq_prep<<<65536 / 256, 256, 0, stream>>>(embed, ws + WS_ET);
    vq_e2<<<NEMB / 256, 256, 0, stream>>>(ws + WS_ET, ws + WS_E2);
    vq_prep_b<<<65536 / 256, 256, 0, stream>>>(embed, eh, el);
    vq_main<<<NROWS / 256, 256, 0, stream>>>(x, mask, eh, el, ws + WS_ET, ws + WS_E2,
                                             out, kwv, ws + WS_LOSS,
                                             rnkb, sort_ok ? hist : (int*)nullptr);
    if (sort_ok) {
        vq_off<<<NEMB / 16, 1024, 0, stream>>>(hist, ws + WS_CNT);
        vq_base<<<1, 1024, 0, stream>>>(ws + WS_CNT, base);
        vq_scatter<<<NROWS / 256, 256, 0, stream>>>(kwv, rnkb, hist, base, sortd);
        vq_gather2<<<NEMB, 512, 0, stream>>>(x, sortd, base, ws + WS_CNT, ws + WS_ESUM);
    } else {
        vq_gather<<<NEMB, 256, 0, stream>>>(x, kwv, ws + WS_ESUM, ws + WS_CNT);
    }
    vq_finalA<<<1, 1024, 0, stream>>>(cluster_size, ws + WS_CNT, ws + WS_LOSS,
                                      out, ws + WS_TOTAL);
    vq_finalB<<<65536 / 256, 256, 0, stream>>>(embed_avg, ws + WS_ESUM, out, ws + WS_TOTAL);
}

// Round 5
// 445.421 us; speedup vs baseline: 1.2607x; 1.2607x over previous
//
#include <hip/hip_runtime.h>

typedef short short8 __attribute__((ext_vector_type(8)));
typedef float f32x16 __attribute__((ext_vector_type(16)));

// Problem constants
#define DIMV   64
#define NEMB   1024
#define NROWS  262144          // B*T = 2048*128
#define DECAYF 0.99f
#define OMDF   0.01f
#define EPSF   1e-5f

// d_out layout (floats): quantize | loss | new_embed | new_cluster_size | new_embed_avg
#define OQ   0
#define OL   16777216
#define OE   16777217
#define ONC  16842753
#define OA   16843777
// EH/EL (bf16 split codebook, MFMA-B-fragment order) live in the d_out tail:
// written by vq_prep_b, read by vq_main, then overwritten by finalA/finalB.
#define OEH  16777216
#define OEL  (16777216 + 32768)

// d_ws layout (floats)
#define WS_E2     0        // 1024: ||e_k||^2
#define WS_CNT    1024     // 1024: int counts (atomic cursors in vq_bucket)
#define WS_ESUM   2048     // 65536: embed_sum, K-MAJOR: [k][d]
#define WS_LOSS   67584    // 1
#define WS_TOTAL  67585    // 1
#define WS_ET     67588    // 65536: embed transposed [k][d] fp32
#define WS_KWV    133124   // 131072 floats = 262144 ushorts: per-row code (0xFFFF = masked)
#define WS_BUCKET 264196   // cap*1024 ints: per-code row-id lists (cap from ws_size)

// RNE float->bf16 (no NaN in data), and back
__device__ __forceinline__ unsigned short f2bf(float f) {
    unsigned u = __float_as_uint(f);
    u = u + 0x7FFFu + ((u >> 16) & 1u);
    return (unsigned short)(u >> 16);
}
__device__ __forceinline__ float bf2f(unsigned short h) {
    return __uint_as_float(((unsigned)h) << 16);
}

// ---------------------------------------------------------------- prep: transpose embed -> et[k][d]
__global__ void vq_prep(const float* __restrict__ embed, float* __restrict__ et)
{
    int idx = blockIdx.x * 256 + threadIdx.x;   // < 65536, idx = d*1024 + k
    int d = idx >> 10;
    int k = idx & (NEMB - 1);
    et[k * DIMV + d] = embed[idx];
}

__global__ void vq_e2(const float* __restrict__ et, float* __restrict__ e2)
{
    int k = blockIdx.x * 256 + threadIdx.x;   // k < 1024
    const float4* ep = (const float4*)(et + k * DIMV);
    float s = 0.f;
    #pragma unroll
    for (int i = 0; i < 16; i++) {
        float4 v = ep[i];
        s = fmaf(v.x, v.x, fmaf(v.y, v.y, fmaf(v.z, v.z, fmaf(v.w, v.w, s))));
    }
    e2[k] = s;
}

// ---------------------------------------------------------------- prep: split codebook into bf16 hi/lo,
// pre-swizzled into 32x32x16 MFMA B-fragment order:
// frag(nt,s): lane L, elem j  <->  B[k = s*16 + (L>>5)*8 + j][n = nt*32 + (L&31)]
__global__ void vq_prep_b(const float* __restrict__ embed,
                          unsigned short* __restrict__ eh,
                          unsigned short* __restrict__ el)
{
    int t = blockIdx.x * 256 + threadIdx.x;    // 0..65535
    int j  = t & 7;
    int L  = (t >> 3) & 63;
    int s  = (t >> 9) & 3;
    int nt = t >> 11;                          // 0..31
    int d    = s * 16 + (L >> 5) * 8 + j;
    int code = nt * 32 + (L & 31);
    float e = embed[d * NEMB + code];
    unsigned short hb = f2bf(e);
    eh[t] = hb;
    el[t] = f2bf(e - bf2f(hb));
}

// ---------------------------------------------------------------- main
// No global atomics except ONE per-wave loss add. EMA inputs are derived from
// kwv[] downstream, so waves retire without an atomic drain.
__global__ __launch_bounds__(256, 2) void vq_main(
    const float* __restrict__ x, const int* __restrict__ mask,
    const unsigned short* __restrict__ eh, const unsigned short* __restrict__ el,
    const float* __restrict__ et, const float* __restrict__ e2g,
    float* __restrict__ out, unsigned short* __restrict__ kwv,
    float* __restrict__ lossacc)
{
    const int tid  = threadIdx.x;
    const int lane = tid & 63;
    const int wid  = tid >> 6;
    const int wbase = blockIdx.x * 256 + wid * 64;   // wave's first row
    const int lm = lane & 31;    // m (A) / n (B) within tile
    const int lh = lane >> 5;    // k-half selector

    // ---- A fragments: xh/xl for 2 M-tiles x 4 K-steps. A[m=lane&31][k=(lane>>5)*8+j]
    short8 ah[2][4], al[2][4];
    #pragma unroll
    for (int mt = 0; mt < 2; mt++) {
        const float* xr = x + (size_t)(wbase + mt * 32 + lm) * DIMV + lh * 8;
        #pragma unroll
        for (int s = 0; s < 4; s++) {
            const float* xp = xr + s * 16;
            #pragma unroll
            for (int j = 0; j < 8; j++) {
                float f = xp[j];
                unsigned short hb = f2bf(f);
                ah[mt][s][j] = (short)hb;
                al[mt][s][j] = (short)f2bf(f - bf2f(hb));
            }
        }
    }

    // per-lane top-2 keys per (mtile, acc-reg); key = (q<<10)|k, q = trunc(2048*(e2-2dot))
    int b1[2][16], b2[2][16];
    #pragma unroll
    for (int mt = 0; mt < 2; mt++)
        #pragma unroll
        for (int r = 0; r < 16; r++) { b1[mt][r] = 0x7FFFFFFF; b2[mt][r] = 0x7FFFFFFF; }

    const short8* ehf = (const short8*)eh;
    const short8* elf = (const short8*)el;

    for (int nt = 0; nt < 32; nt++) {
        short8 bh[4], bl[4];
        #pragma unroll
        for (int s = 0; s < 4; s++) {
            bh[s] = ehf[(nt * 4 + s) * 64 + lane];
            bl[s] = elf[(nt * 4 + s) * 64 + lane];
        }
        const int   klane = nt * 32 + lm;
        const float e2s   = e2g[klane] * 2048.0f;

        f32x16 acc0, acc1;
        #pragma unroll
        for (int i = 0; i < 16; i++) { acc0[i] = 0.0f; acc1[i] = 0.0f; }

        #pragma unroll
        for (int s = 0; s < 4; s++) {   // pass hh
            acc0 = __builtin_amdgcn_mfma_f32_32x32x16_bf16(ah[0][s], bh[s], acc0, 0, 0, 0);
            acc1 = __builtin_amdgcn_mfma_f32_32x32x16_bf16(ah[1][s], bh[s], acc1, 0, 0, 0);
        }
        #pragma unroll
        for (int s = 0; s < 4; s++) {   // pass hl
            acc0 = __builtin_amdgcn_mfma_f32_32x32x16_bf16(ah[0][s], bl[s], acc0, 0, 0, 0);
            acc1 = __builtin_amdgcn_mfma_f32_32x32x16_bf16(ah[1][s], bl[s], acc1, 0, 0, 0);
        }
        #pragma unroll
        for (int s = 0; s < 4; s++) {   // pass lh
            acc0 = __builtin_amdgcn_mfma_f32_32x32x16_bf16(al[0][s], bh[s], acc0, 0, 0, 0);
            acc1 = __builtin_amdgcn_mfma_f32_32x32x16_bf16(al[1][s], bh[s], acc1, 0, 0, 0);
        }

        #pragma unroll
        for (int r = 0; r < 16; r++) {
            int q0   = (int)fmaf(acc0[r], -4096.0f, e2s);     // 2048*(e2-2dot), trunc
            int key0 = (int)(((unsigned)q0) << 10) | klane;
            int lo0 = min(b1[0][r], key0), hi0 = max(b1[0][r], key0);
            b1[0][r] = lo0; b2[0][r] = min(b2[0][r], hi0);

            int q1   = (int)fmaf(acc1[r], -4096.0f, e2s);
            int key1 = (int)(((unsigned)q1) << 10) | klane;
            int lo1 = min(b1[1][r], key1), hi1 = max(b1[1][r], key1);
            b1[1][r] = lo1; b2[1][r] = min(b2[1][r], hi1);
        }
    }

    // ---- cross-lane reduction (per half-wave = 32 lanes sharing a row) ----
    int sm1 = 0x7FFFFFFF, sm2 = 0x7FFFFFFF, sc = 1;
    unsigned long long hm = (lane < 32) ? 0xFFFFFFFFull : 0xFFFFFFFF00000000ull;
    #pragma unroll
    for (int mt = 0; mt < 2; mt++) {
        #pragma unroll
        for (int r = 0; r < 16; r++) {
            int v1 = b1[mt][r], v2 = b2[mt][r];
            #pragma unroll
            for (int m = 1; m <= 16; m <<= 1) {
                int o1 = __shfl_xor(v1, m, 64);
                int o2 = __shfl_xor(v2, m, 64);
                int lo = min(v1, o1), hi = max(v1, o1);
                v1 = lo;
                v2 = min(min(v2, o2), hi);
            }
            int thr = (v1 >> 10) + 41;   // window = 41/2048 ~= 0.02
            bool in1 = (b1[mt][r] >> 10) <= thr;
            bool in2 = (b2[mt][r] >> 10) <= thr;
            unsigned long long B1 = __ballot(in1), B2 = __ballot(in2);
            int cnt = (int)__popcll(B1 & hm) + (int)__popcll(B2 & hm);
            int w1a = __shfl(v1, 0, 64),  w2a = __shfl(v2, 0, 64),  ca = __shfl(cnt, 0, 64);
            int w1b = __shfl(v1, 32, 64), w2b = __shfl(v2, 32, 64), cb = __shfl(cnt, 32, 64);
            int r0 = mt * 32 + (r & 3) + 8 * (r >> 2);
            if (lane == r0)     { sm1 = w1a; sm2 = w2a; sc = ca; }
            if (lane == r0 + 4) { sm1 = w1b; sm2 = w2b; sc = cb; }
        }
    }

    // ---- per-lane epilogue: lane owns row wbase+lane ----
    const int row = wbase + lane;
    int kw = sm1 & 1023;

    // ---- wave-cooperative exact full scan for sc>=3 rows (rare path).
    {
        unsigned long long fm = __ballot(sc >= 3);
        while (fm) {
            int j = __ffsll(fm) - 1; fm &= (fm - 1);
            const float4* xr = (const float4*)(x + (size_t)(wbase + j) * DIMV);
            float4 xb[16];
            float xb2 = 0.f;
            #pragma unroll
            for (int i = 0; i < 16; i++) {
                float4 v = xr[i];                 // broadcast load (same addr all lanes)
                xb[i] = v;
                xb2 += v.x * v.x + v.y * v.y + v.z * v.z + v.w * v.w;
            }
            float bd = 3.4e38f; int bc = 0;
            for (int t = 0; t < 16; t++) {
                int c = lane + (t << 6);
                const float4* ep = (const float4*)(et + (c << 6));
                float ax = 0.f, ay = 0.f, az = 0.f, aw = 0.f;
                #pragma unroll 4
                for (int i = 0; i < 16; i++) {
                    float4 ev = ep[i];
                    ax = fmaf(xb[i].x, ev.x, ax);
                    ay = fmaf(xb[i].y, ev.y, ay);
                    az = fmaf(xb[i].z, ev.z, az);
                    aw = fmaf(xb[i].w, ev.w, aw);
                }
                float dot = (ax + ay) + (az + aw);
                float d = (xb2 - 2.0f * dot) + e2g[c];
                if (d < bd) { bd = d; bc = c; }   // ascending c: lowest idx on ties
            }
            #pragma unroll
            for (int m = 1; m < 64; m <<= 1) {    // lexicographic (dist, idx) min
                float od = __shfl_xor(bd, m, 64);
                int   oc = __shfl_xor(bc, m, 64);
                if (od < bd || (od == bd && oc < bc)) { bd = od; bc = oc; }
            }
            if (lane == j) kw = bc;
        }
    }

    float4 xv[16];
    {
        const float4* xp = (const float4*)(x + (size_t)row * DIMV);
        #pragma unroll
        for (int i = 0; i < 16; i++) xv[i] = xp[i];
    }

    if (sc == 2) {
        // exact recheck of the two candidates
        float x2 = 0.f;
        #pragma unroll
        for (int i = 0; i < 16; i++)
            x2 += xv[i].x * xv[i].x + xv[i].y * xv[i].y + xv[i].z * xv[i].z + xv[i].w * xv[i].w;

        auto fdist = [&](int k) -> float {
            const float4* ep = (const float4*)(et + (k << 6));
            float ax = 0.f, ay = 0.f, az = 0.f, aw = 0.f;
            #pragma unroll
            for (int i = 0; i < 16; i++) {
                float4 ev = ep[i];
                ax = fmaf(xv[i].x, ev.x, ax);
                ay = fmaf(xv[i].y, ev.y, ay);
                az = fmaf(xv[i].z, ev.z, az);
                aw = fmaf(xv[i].w, ev.w, aw);
            }
            float dot = (ax + ay) + (az + aw);
            return (x2 - 2.0f * dot) + e2g[k];
        };

        int k2 = sm2 & 1023;
        float d1 = fdist(kw);
        float d2 = fdist(k2);
        if (d2 < d1 || (d2 == d1 && k2 < kw)) kw = k2;
    }

    const bool valid = (mask[row] == 0);   // valid = ~mask
    float sq = 0.f;
    float4* qp = (float4*)(out + OQ + (size_t)row * DIMV);
    const float4* erow = (const float4*)(et + (kw << 6));
    #pragma unroll
    for (int i = 0; i < 16; i++) {
        float4 xvv = xv[i];
        float4 ev  = erow[i];
        float q0 = xvv.x + (ev.x - xvv.x);
        float q1 = xvv.y + (ev.y - xvv.y);
        float q2 = xvv.z + (ev.z - xvv.z);
        float q3 = xvv.w + (ev.w - xvv.w);
        float4 q4 = {q0, q1, q2, q3};
        qp[i] = q4;
        float d0 = q0 - xvv.x, d1 = q1 - xvv.y, d2 = q2 - xvv.z, d3 = q3 - xvv.w;
        sq += d0 * d0 + d1 * d1 + d2 * d2 + d3 * d3;
    }

    // per-row code record: ONE plain coalesced 2B store, no atomics.
    kwv[row] = valid ? (unsigned short)kw : (unsigned short)0xFFFF;

    float v = valid ? sq : 0.0f;
    #pragma unroll
    for (int off = 32; off > 0; off >>= 1) v += __shfl_down(v, off, 64);
    if (lane == 0) atomicAdd(lossacc, v);
}

// ---------------------------------------------------------------- bucket append (dedicated kernel:
// the returning atomic's latency/drain lives HERE, not on vq_main's critical path).
// One int atomicAdd per valid row on 1024 cursors; 32-wave occupancy hides latency.
// Overflow (cnt > cap): fire-and-forget fp atomics into pre-zeroed esum — rare, correct for any skew.
__global__ __launch_bounds__(256) void vq_bucket(
    const unsigned short* __restrict__ kwv, const float* __restrict__ x,
    int* __restrict__ cnt, int* __restrict__ bucket,
    float* __restrict__ esum, int cap)
{
    int row = blockIdx.x * 256 + threadIdx.x;
    unsigned short c = kwv[row];
    if (c == 0xFFFFu) return;
    int pos = atomicAdd(&cnt[c], 1);
    if (pos < cap) {
        bucket[(size_t)c * cap + pos] = row;
    } else {
        const float* xr = x + (size_t)row * DIMV;
        float* ep = esum + ((int)c << 6);
        #pragma unroll 8
        for (int i = 0; i < DIMV; i++) atomicAdd(ep + i, xr[i]);
    }
}

// ---------------------------------------------------------------- per-code gather-sum.
// Round-1 calibrated this structure at ~95 us with 1 wave/8-deep on the hot code;
// here 8 waves x 8-deep cuts the hot code's serial depth 8x. Rows for code c are
// contiguous in bucket[c*cap..]; x row reads fully coalesced (d = lane).
// esum '+=' (not '=') keeps overflow-path atomic contributions; exclusive owner per code.
__global__ __launch_bounds__(512) void vq_esum(
    const float* __restrict__ x, const int* __restrict__ cnt,
    const int* __restrict__ bucket, float* __restrict__ esum, int cap)
{
    const int tid  = threadIdx.x;
    const int lane = tid & 63;
    const int wid  = tid >> 6;      // 0..7
    const int c    = blockIdx.x;
    const int n    = min(cnt[c], cap);
    const int* bp  = bucket + (size_t)c * cap;
    __shared__ float part[8][64];

    float acc = 0.f;
    for (int i = wid * 8; i < n; i += 64) {
        float tmp[8];
        if (i + 8 <= n) {
            // bulk: two 16B broadcast loads of 8 contiguous row-ids (cap is 8-aligned)
            int4 a = *(const int4*)(bp + i);
            int4 b = *(const int4*)(bp + i + 4);
            tmp[0] = x[(size_t)a.x * DIMV + lane];
            tmp[1] = x[(size_t)a.y * DIMV + lane];
            tmp[2] = x[(size_t)a.z * DIMV + lane];
            tmp[3] = x[(size_t)a.w * DIMV + lane];
            tmp[4] = x[(size_t)b.x * DIMV + lane];
            tmp[5] = x[(size_t)b.y * DIMV + lane];
            tmp[6] = x[(size_t)b.z * DIMV + lane];
            tmp[7] = x[(size_t)b.w * DIMV + lane];
        } else {
            #pragma unroll
            for (int k = 0; k < 8; k++) {
                int idx = i + k;
                tmp[k] = (idx < n) ? x[(size_t)bp[idx] * DIMV + lane] : 0.f;
            }
        }
        acc += ((tmp[0] + tmp[1]) + (tmp[2] + tmp[3]))
             + ((tmp[4] + tmp[5]) + (tmp[6] + tmp[7]));
    }

    part[wid][lane] = acc;
    __syncthreads();
    if (tid < 64) {
        float s = 0.f;
        #pragma unroll
        for (int w = 0; w < 8; w++) s += part[w][lane];
        esum[(c << 6) + lane] += s;   // += keeps overflow atomics (esum pre-zeroed)
    }
}

// ---------------------------------------------------------------- finalize A
__global__ __launch_bounds__(1024) void vq_finalA(
    const float* __restrict__ cluster_size, const int* __restrict__ counts,
    const float* __restrict__ lossacc, float* __restrict__ out,
    float* __restrict__ total_ws)
{
    __shared__ float s1[1024];
    __shared__ float s2[1024];
    int k = threadIdx.x;
    float c   = (float)counts[k];
    float ncs = cluster_size[k] * DECAYF + OMDF * c;
    out[ONC + k] = ncs;
    s1[k] = ncs; s2[k] = c;
    __syncthreads();
    for (int off = 512; off > 0; off >>= 1) {
        if (k < off) { s1[k] += s1[k + off]; s2[k] += s2[k + off]; }
        __syncthreads();
    }
    if (k == 0) {
        total_ws[0] = s1[0];
        out[OL] = lossacc[0] / (s2[0] * (float)DIMV);
    }
}

// ---------------------------------------------------------------- finalize B (esum is k-major)
__global__ void vq_finalB(const float* __restrict__ embed_avg,
                          const float* __restrict__ esum,
                          float* __restrict__ out,
                          const float* __restrict__ total_ws)
{
    int idx = blockIdx.x * 256 + threadIdx.x;  // < 65536, idx = d*1024 + k
    int k = idx & (NEMB - 1);
    int d = idx >> 10;
    float avg = embed_avg[idx] * DECAYF + OMDF * esum[(k << 6) + d];
    out[OA + idx] = avg;
    float ncs   = out[ONC + k];
    float total = *total_ws;
    float sm = (ncs + EPSF) / (total + (float)NEMB * EPSF) * total;
    out[OE + idx] = avg / sm;
}

// ---------------------------------------------------------------- launcher
extern "C" void kernel_launch(void* const* d_in, const int* in_sizes, int n_in,
                              void* d_out, int out_size, void* d_ws, size_t ws_size,
                              hipStream_t stream)
{
    const float* x            = (const float*)d_in[0];
    const int*   mask         = (const int*)d_in[1];
    const float* embed        = (const float*)d_in[2];
    const float* cluster_size = (const float*)d_in[3];
    const float* embed_avg    = (const float*)d_in[4];
    float* out = (float*)d_out;
    float* ws  = (float*)d_ws;

    unsigned short* eh   = (unsigned short*)(out + OEH);
    unsigned short* el   = (unsigned short*)(out + OEL);
    unsigned short* kwv  = (unsigned short*)(ws + WS_KWV);
    int*            cnt  = (int*)(ws + WS_CNT);
    int*            bucket = (int*)(ws + WS_BUCKET);

    // bucket capacity from available workspace (8-aligned for int4 reads);
    // cap == 0 -> all rows take the overflow-atomic path (slow but correct).
    int cap = 0;
    size_t avail = ws_size / sizeof(float);
    if (avail > (size_t)WS_BUCKET) {
        size_t per = (avail - (size_t)WS_BUCKET) / (size_t)NEMB;
        if (per > 4096) per = 4096;
        cap = (int)per & ~7;
    }

    // zero counts + esum + loss + total (contiguous span)
    hipMemsetAsync(ws + WS_CNT, 0, (size_t)(WS_TOTAL + 1 - WS_CNT) * sizeof(float), stream);

    vq_prep<<<65536 / 256, 256, 0, stream>>>(embed, ws + WS_ET);
    vq_e2<<<NEMB / 256, 256, 0, stream>>>(ws + WS_ET, ws + WS_E2);
    vq_prep_b<<<65536 / 256, 256, 0, stream>>>(embed, eh, el);
    vq_main<<<NROWS / 256, 256, 0, stream>>>(x, mask, eh, el, ws + WS_ET, ws + WS_E2,
                                             out, kwv, ws + WS_LOSS);
    vq_bucket<<<NROWS / 256, 256, 0, stream>>>(kwv, x, cnt, bucket, ws + WS_ESUM, cap);
    vq_esum<<<NEMB, 512, 0, stream>>>(x, cnt, bucket, ws + WS_ESUM, cap);
    vq_finalA<<<1, 1024, 0, stream>>>(cluster_size, cnt, ws + WS_LOSS,
                                      out, ws + WS_TOTAL);
    vq_finalB<<<65536 / 256, 256, 0, stream>>>(embed_avg, ws + WS_ESUM, out, ws + WS_TOTAL);
}

// Round 6
// 378.447 us; speedup vs baseline: 1.4838x; 1.1770x over previous
//
#include <hip/hip_runtime.h>

typedef short short8 __attribute__((ext_vector_type(8)));
typedef float f32x16 __attribute__((ext_vector_type(16)));

// Problem constants
#define DIMV   64
#define NEMB   1024
#define NROWS  262144          // B*T = 2048*128
#define DECAYF 0.99f
#define OMDF   0.01f
#define EPSF   1e-5f
#define NSH    8               // bucket cursor shards (parallelize atomic drain)

// d_out layout (floats): quantize | loss | new_embed | new_cluster_size | new_embed_avg
#define OQ   0
#define OL   16777216
#define OE   16777217
#define ONC  16842753
#define OA   16843777
// EH/EL (bf16 split codebook, MFMA-B-fragment order) live in the d_out tail:
// written by vq_prep_b, read by vq_main, then overwritten by finalA/finalB.
#define OEH  16777216
#define OEL  (16777216 + 32768)

// d_ws layout (floats)
#define WS_E2     0        // 1024: ||e_k||^2
#define WS_CNT    1024     // 8192 ints: sharded cursors cnt[c + 1024*s]
#define WS_ESUM   9216     // 65536: embed_sum, K-MAJOR: [k][d]
#define WS_LOSSP  74752    // 1024: per-block loss partials (plain stores)
#define WS_TOTAL  75776    // 1
#define WS_ET     75780    // 65536: embed transposed [k][d] fp32
#define WS_KWV    141316   // 131072 floats = 262144 ushorts: per-row code (0xFFFF = masked)
#define WS_BUCKET 272388   // NSH*NEMB*capS ints: per-(shard,code) row-id lists

// RNE float->bf16 (no NaN in data), and back
__device__ __forceinline__ unsigned short f2bf(float f) {
    unsigned u = __float_as_uint(f);
    u = u + 0x7FFFu + ((u >> 16) & 1u);
    return (unsigned short)(u >> 16);
}
__device__ __forceinline__ float bf2f(unsigned short h) {
    return __uint_as_float(((unsigned)h) << 16);
}

// ---------------------------------------------------------------- prep: transpose embed -> et[k][d]
__global__ void vq_prep(const float* __restrict__ embed, float* __restrict__ et)
{
    int idx = blockIdx.x * 256 + threadIdx.x;   // < 65536, idx = d*1024 + k
    int d = idx >> 10;
    int k = idx & (NEMB - 1);
    et[k * DIMV + d] = embed[idx];
}

__global__ void vq_e2(const float* __restrict__ et, float* __restrict__ e2)
{
    int k = blockIdx.x * 256 + threadIdx.x;   // k < 1024
    const float4* ep = (const float4*)(et + k * DIMV);
    float s = 0.f;
    #pragma unroll
    for (int i = 0; i < 16; i++) {
        float4 v = ep[i];
        s = fmaf(v.x, v.x, fmaf(v.y, v.y, fmaf(v.z, v.z, fmaf(v.w, v.w, s))));
    }
    e2[k] = s;
}

// ---------------------------------------------------------------- prep: split codebook into bf16 hi/lo,
// pre-swizzled into 32x32x16 MFMA B-fragment order:
// frag(nt,s): lane L, elem j  <->  B[k = s*16 + (L>>5)*8 + j][n = nt*32 + (L&31)]
__global__ void vq_prep_b(const float* __restrict__ embed,
                          unsigned short* __restrict__ eh,
                          unsigned short* __restrict__ el)
{
    int t = blockIdx.x * 256 + threadIdx.x;    // 0..65535
    int j  = t & 7;
    int L  = (t >> 3) & 63;
    int s  = (t >> 9) & 3;
    int nt = t >> 11;                          // 0..31
    int d    = s * 16 + (L >> 5) * 8 + j;
    int code = nt * 32 + (L & 31);
    float e = embed[d * NEMB + code];
    unsigned short hb = f2bf(e);
    eh[t] = hb;
    el[t] = f2bf(e - bf2f(hb));
}

// ---------------------------------------------------------------- main
// ZERO global atomics. The old single-address loss atomicAdd (4096 serialized
// device-scope RMWs on one line) was a ~170 us end-of-dispatch drain — the
// dispatch can't complete until they land. Loss is now per-block plain stores.
__global__ __launch_bounds__(256, 2) void vq_main(
    const float* __restrict__ x, const int* __restrict__ mask,
    const unsigned short* __restrict__ eh, const unsigned short* __restrict__ el,
    const float* __restrict__ et, const float* __restrict__ e2g,
    float* __restrict__ out, unsigned short* __restrict__ kwv,
    float* __restrict__ loss_part)
{
    const int tid  = threadIdx.x;
    const int lane = tid & 63;
    const int wid  = tid >> 6;
    const int wbase = blockIdx.x * 256 + wid * 64;   // wave's first row
    const int lm = lane & 31;    // m (A) / n (B) within tile
    const int lh = lane >> 5;    // k-half selector

    __shared__ float lw[4];

    // ---- A fragments: xh/xl for 2 M-tiles x 4 K-steps. A[m=lane&31][k=(lane>>5)*8+j]
    short8 ah[2][4], al[2][4];
    #pragma unroll
    for (int mt = 0; mt < 2; mt++) {
        const float* xr = x + (size_t)(wbase + mt * 32 + lm) * DIMV + lh * 8;
        #pragma unroll
        for (int s = 0; s < 4; s++) {
            const float* xp = xr + s * 16;
            #pragma unroll
            for (int j = 0; j < 8; j++) {
                float f = xp[j];
                unsigned short hb = f2bf(f);
                ah[mt][s][j] = (short)hb;
                al[mt][s][j] = (short)f2bf(f - bf2f(hb));
            }
        }
    }

    // per-lane top-2 keys per (mtile, acc-reg); key = (q<<10)|k, q = trunc(2048*(e2-2dot))
    int b1[2][16], b2[2][16];
    #pragma unroll
    for (int mt = 0; mt < 2; mt++)
        #pragma unroll
        for (int r = 0; r < 16; r++) { b1[mt][r] = 0x7FFFFFFF; b2[mt][r] = 0x7FFFFFFF; }

    const short8* ehf = (const short8*)eh;
    const short8* elf = (const short8*)el;

    for (int nt = 0; nt < 32; nt++) {
        short8 bh[4], bl[4];
        #pragma unroll
        for (int s = 0; s < 4; s++) {
            bh[s] = ehf[(nt * 4 + s) * 64 + lane];
            bl[s] = elf[(nt * 4 + s) * 64 + lane];
        }
        const int   klane = nt * 32 + lm;
        const float e2s   = e2g[klane] * 2048.0f;

        f32x16 acc0, acc1;
        #pragma unroll
        for (int i = 0; i < 16; i++) { acc0[i] = 0.0f; acc1[i] = 0.0f; }

        #pragma unroll
        for (int s = 0; s < 4; s++) {   // pass hh
            acc0 = __builtin_amdgcn_mfma_f32_32x32x16_bf16(ah[0][s], bh[s], acc0, 0, 0, 0);
            acc1 = __builtin_amdgcn_mfma_f32_32x32x16_bf16(ah[1][s], bh[s], acc1, 0, 0, 0);
        }
        #pragma unroll
        for (int s = 0; s < 4; s++) {   // pass hl
            acc0 = __builtin_amdgcn_mfma_f32_32x32x16_bf16(ah[0][s], bl[s], acc0, 0, 0, 0);
            acc1 = __builtin_amdgcn_mfma_f32_32x32x16_bf16(ah[1][s], bl[s], acc1, 0, 0, 0);
        }
        #pragma unroll
        for (int s = 0; s < 4; s++) {   // pass lh
            acc0 = __builtin_amdgcn_mfma_f32_32x32x16_bf16(al[0][s], bh[s], acc0, 0, 0, 0);
            acc1 = __builtin_amdgcn_mfma_f32_32x32x16_bf16(al[1][s], bh[s], acc1, 0, 0, 0);
        }

        #pragma unroll
        for (int r = 0; r < 16; r++) {
            int q0   = (int)fmaf(acc0[r], -4096.0f, e2s);     // 2048*(e2-2dot), trunc
            int key0 = (int)(((unsigned)q0) << 10) | klane;
            int lo0 = min(b1[0][r], key0), hi0 = max(b1[0][r], key0);
            b1[0][r] = lo0; b2[0][r] = min(b2[0][r], hi0);

            int q1   = (int)fmaf(acc1[r], -4096.0f, e2s);
            int key1 = (int)(((unsigned)q1) << 10) | klane;
            int lo1 = min(b1[1][r], key1), hi1 = max(b1[1][r], key1);
            b1[1][r] = lo1; b2[1][r] = min(b2[1][r], hi1);
        }
    }

    // ---- cross-lane reduction (per half-wave = 32 lanes sharing a row) ----
    int sm1 = 0x7FFFFFFF, sm2 = 0x7FFFFFFF, sc = 1;
    unsigned long long hm = (lane < 32) ? 0xFFFFFFFFull : 0xFFFFFFFF00000000ull;
    #pragma unroll
    for (int mt = 0; mt < 2; mt++) {
        #pragma unroll
        for (int r = 0; r < 16; r++) {
            int v1 = b1[mt][r], v2 = b2[mt][r];
            #pragma unroll
            for (int m = 1; m <= 16; m <<= 1) {
                int o1 = __shfl_xor(v1, m, 64);
                int o2 = __shfl_xor(v2, m, 64);
                int lo = min(v1, o1), hi = max(v1, o1);
                v1 = lo;
                v2 = min(min(v2, o2), hi);
            }
            int thr = (v1 >> 10) + 41;   // window = 41/2048 ~= 0.02
            bool in1 = (b1[mt][r] >> 10) <= thr;
            bool in2 = (b2[mt][r] >> 10) <= thr;
            unsigned long long B1 = __ballot(in1), B2 = __ballot(in2);
            int cnt = (int)__popcll(B1 & hm) + (int)__popcll(B2 & hm);
            int w1a = __shfl(v1, 0, 64),  w2a = __shfl(v2, 0, 64),  ca = __shfl(cnt, 0, 64);
            int w1b = __shfl(v1, 32, 64), w2b = __shfl(v2, 32, 64), cb = __shfl(cnt, 32, 64);
            int r0 = mt * 32 + (r & 3) + 8 * (r >> 2);
            if (lane == r0)     { sm1 = w1a; sm2 = w2a; sc = ca; }
            if (lane == r0 + 4) { sm1 = w1b; sm2 = w2b; sc = cb; }
        }
    }

    // ---- per-lane epilogue: lane owns row wbase+lane ----
    const int row = wbase + lane;
    int kw = sm1 & 1023;

    // ---- wave-cooperative exact full scan for sc>=3 rows (rare path).
    {
        unsigned long long fm = __ballot(sc >= 3);
        while (fm) {
            int j = __ffsll(fm) - 1; fm &= (fm - 1);
            const float4* xr = (const float4*)(x + (size_t)(wbase + j) * DIMV);
            float4 xb[16];
            float xb2 = 0.f;
            #pragma unroll
            for (int i = 0; i < 16; i++) {
                float4 v = xr[i];                 // broadcast load (same addr all lanes)
                xb[i] = v;
                xb2 += v.x * v.x + v.y * v.y + v.z * v.z + v.w * v.w;
            }
            float bd = 3.4e38f; int bc = 0;
            for (int t = 0; t < 16; t++) {
                int c = lane + (t << 6);
                const float4* ep = (const float4*)(et + (c << 6));
                float ax = 0.f, ay = 0.f, az = 0.f, aw = 0.f;
                #pragma unroll 4
                for (int i = 0; i < 16; i++) {
                    float4 ev = ep[i];
                    ax = fmaf(xb[i].x, ev.x, ax);
                    ay = fmaf(xb[i].y, ev.y, ay);
                    az = fmaf(xb[i].z, ev.z, az);
                    aw = fmaf(xb[i].w, ev.w, aw);
                }
                float dot = (ax + ay) + (az + aw);
                float d = (xb2 - 2.0f * dot) + e2g[c];
                if (d < bd) { bd = d; bc = c; }   // ascending c: lowest idx on ties
            }
            #pragma unroll
            for (int m = 1; m < 64; m <<= 1) {    // lexicographic (dist, idx) min
                float od = __shfl_xor(bd, m, 64);
                int   oc = __shfl_xor(bc, m, 64);
                if (od < bd || (od == bd && oc < bc)) { bd = od; bc = oc; }
            }
            if (lane == j) kw = bc;
        }
    }

    float4 xv[16];
    {
        const float4* xp = (const float4*)(x + (size_t)row * DIMV);
        #pragma unroll
        for (int i = 0; i < 16; i++) xv[i] = xp[i];
    }

    if (sc == 2) {
        // exact recheck of the two candidates
        float x2 = 0.f;
        #pragma unroll
        for (int i = 0; i < 16; i++)
            x2 += xv[i].x * xv[i].x + xv[i].y * xv[i].y + xv[i].z * xv[i].z + xv[i].w * xv[i].w;

        auto fdist = [&](int k) -> float {
            const float4* ep = (const float4*)(et + (k << 6));
            float ax = 0.f, ay = 0.f, az = 0.f, aw = 0.f;
            #pragma unroll
            for (int i = 0; i < 16; i++) {
                float4 ev = ep[i];
                ax = fmaf(xv[i].x, ev.x, ax);
                ay = fmaf(xv[i].y, ev.y, ay);
                az = fmaf(xv[i].z, ev.z, az);
                aw = fmaf(xv[i].w, ev.w, aw);
            }
            float dot = (ax + ay) + (az + aw);
            return (x2 - 2.0f * dot) + e2g[k];
        };

        int k2 = sm2 & 1023;
        float d1 = fdist(kw);
        float d2 = fdist(k2);
        if (d2 < d1 || (d2 == d1 && k2 < kw)) kw = k2;
    }

    const bool valid = (mask[row] == 0);   // valid = ~mask
    float sq = 0.f;
    float4* qp = (float4*)(out + OQ + (size_t)row * DIMV);
    const float4* erow = (const float4*)(et + (kw << 6));
    #pragma unroll
    for (int i = 0; i < 16; i++) {
        float4 xvv = xv[i];
        float4 ev  = erow[i];
        float q0 = xvv.x + (ev.x - xvv.x);
        float q1 = xvv.y + (ev.y - xvv.y);
        float q2 = xvv.z + (ev.z - xvv.z);
        float q3 = xvv.w + (ev.w - xvv.w);
        float4 q4 = {q0, q1, q2, q3};
        qp[i] = q4;
        float d0 = q0 - xvv.x, d1 = q1 - xvv.y, d2 = q2 - xvv.z, d3 = q3 - xvv.w;
        sq += d0 * d0 + d1 * d1 + d2 * d2 + d3 * d3;
    }

    // per-row code record: ONE plain coalesced 2B store, no atomics.
    kwv[row] = valid ? (unsigned short)kw : (unsigned short)0xFFFF;

    // per-block loss partial: shuffle -> LDS -> ONE plain store. No atomics anywhere.
    float v = valid ? sq : 0.0f;
    #pragma unroll
    for (int off = 32; off > 0; off >>= 1) v += __shfl_down(v, off, 64);
    if (lane == 0) lw[wid] = v;
    __syncthreads();
    if (tid == 0) loss_part[blockIdx.x] = (lw[0] + lw[1]) + (lw[2] + lw[3]);
}

// ---------------------------------------------------------------- bucket append (dedicated kernel).
// Cursors sharded 8x by source block: cnt[c + 1024*s]. The hot code's ~6K RMWs
// split across 8 cache lines/pages -> ~8x shorter serialized drain than round 5.
// Overflow (pos >= capS): fire-and-forget fp atomics into pre-zeroed esum.
__global__ __launch_bounds__(256) void vq_bucket(
    const unsigned short* __restrict__ kwv, const float* __restrict__ x,
    int* __restrict__ cnt, int* __restrict__ bucket,
    float* __restrict__ esum, int capS)
{
    int row = blockIdx.x * 256 + threadIdx.x;
    unsigned short c = kwv[row];
    if (c == 0xFFFFu) return;
    int s = blockIdx.x & (NSH - 1);
    int pos = atomicAdd(&cnt[(int)c + (s << 10)], 1);
    if (pos < capS) {
        bucket[((size_t)s * NEMB + (int)c) * capS + pos] = row;
    } else {
        const float* xr = x + (size_t)row * DIMV;
        float* ep = esum + ((int)c << 6);
        #pragma unroll 8
        for (int i = 0; i < DIMV; i++) atomicAdd(ep + i, xr[i]);
    }
}

// ---------------------------------------------------------------- per-code gather-sum.
// Block per code, 8 waves; wave w owns shard w (hot code auto-balanced ~n/8 per
// wave). 8-deep load ILP, fully-coalesced 256B row reads (d = lane).
// esum '+=' keeps overflow-path atomic contributions; exclusive owner per code.
__global__ __launch_bounds__(512) void vq_esum(
    const float* __restrict__ x, const int* __restrict__ cnt,
    const int* __restrict__ bucket, float* __restrict__ esum, int capS)
{
    const int tid  = threadIdx.x;
    const int lane = tid & 63;
    const int wid  = tid >> 6;      // 0..7 = shard
    const int c    = blockIdx.x;
    const int n    = min(cnt[c + (wid << 10)], capS);
    const int* bp  = bucket + ((size_t)wid * NEMB + c) * capS;
    __shared__ float part[8][64];

    float acc = 0.f;
    for (int i = 0; i < n; i += 8) {
        float tmp[8];
        if (i + 8 <= n) {
            // bulk: two 16B broadcast loads of 8 contiguous row-ids (capS is 8-aligned)
            int4 a = *(const int4*)(bp + i);
            int4 b = *(const int4*)(bp + i + 4);
            tmp[0] = x[(size_t)a.x * DIMV + lane];
            tmp[1] = x[(size_t)a.y * DIMV + lane];
            tmp[2] = x[(size_t)a.z * DIMV + lane];
            tmp[3] = x[(size_t)a.w * DIMV + lane];
            tmp[4] = x[(size_t)b.x * DIMV + lane];
            tmp[5] = x[(size_t)b.y * DIMV + lane];
            tmp[6] = x[(size_t)b.z * DIMV + lane];
            tmp[7] = x[(size_t)b.w * DIMV + lane];
        } else {
            #pragma unroll
            for (int k = 0; k < 8; k++) {
                int idx = i + k;
                tmp[k] = (idx < n) ? x[(size_t)bp[idx] * DIMV + lane] : 0.f;
            }
        }
        acc += ((tmp[0] + tmp[1]) + (tmp[2] + tmp[3]))
             + ((tmp[4] + tmp[5]) + (tmp[6] + tmp[7]));
    }

    part[wid][lane] = acc;
    __syncthreads();
    if (tid < 64) {
        float s = 0.f;
        #pragma unroll
        for (int w = 0; w < 8; w++) s += part[w][lane];
        esum[(c << 6) + lane] += s;   // += keeps overflow atomics (esum pre-zeroed)
    }
}

// ---------------------------------------------------------------- finalize A
// counts = sum of 8 shard cursors; loss = tree-reduce of 1024 per-block partials.
__global__ __launch_bounds__(1024) void vq_finalA(
    const float* __restrict__ cluster_size, const int* __restrict__ cnt,
    const float* __restrict__ loss_part, float* __restrict__ out,
    float* __restrict__ total_ws)
{
    __shared__ float s1[1024];
    __shared__ float s2[1024];
    __shared__ float s3[1024];
    int k = threadIdx.x;
    int ci = 0;
    #pragma unroll
    for (int s = 0; s < NSH; s++) ci += cnt[k + (s << 10)];
    float c   = (float)ci;
    float ncs = cluster_size[k] * DECAYF + OMDF * c;
    out[ONC + k] = ncs;
    s1[k] = ncs; s2[k] = c; s3[k] = loss_part[k];
    __syncthreads();
    for (int off = 512; off > 0; off >>= 1) {
        if (k < off) { s1[k] += s1[k + off]; s2[k] += s2[k + off]; s3[k] += s3[k + off]; }
        __syncthreads();
    }
    if (k == 0) {
        total_ws[0] = s1[0];
        out[OL] = s3[0] / (s2[0] * (float)DIMV);
    }
}

// ---------------------------------------------------------------- finalize B (esum is k-major)
__global__ void vq_finalB(const float* __restrict__ embed_avg,
                          const float* __restrict__ esum,
                          float* __restrict__ out,
                          const float* __restrict__ total_ws)
{
    int idx = blockIdx.x * 256 + threadIdx.x;  // < 65536, idx = d*1024 + k
    int k = idx & (NEMB - 1);
    int d = idx >> 10;
    float avg = embed_avg[idx] * DECAYF + OMDF * esum[(k << 6) + d];
    out[OA + idx] = avg;
    float ncs   = out[ONC + k];
    float total = *total_ws;
    float sm = (ncs + EPSF) / (total + (float)NEMB * EPSF) * total;
    out[OE + idx] = avg / sm;
}

// ---------------------------------------------------------------- launcher
extern "C" void kernel_launch(void* const* d_in, const int* in_sizes, int n_in,
                              void* d_out, int out_size, void* d_ws, size_t ws_size,
                              hipStream_t stream)
{
    const float* x            = (const float*)d_in[0];
    const int*   mask         = (const int*)d_in[1];
    const float* embed        = (const float*)d_in[2];
    const float* cluster_size = (const float*)d_in[3];
    const float* embed_avg    = (const float*)d_in[4];
    float* out = (float*)d_out;
    float* ws  = (float*)d_ws;

    unsigned short* eh     = (unsigned short*)(out + OEH);
    unsigned short* el     = (unsigned short*)(out + OEL);
    unsigned short* kwv    = (unsigned short*)(ws + WS_KWV);
    int*            cnt    = (int*)(ws + WS_CNT);
    int*            bucket = (int*)(ws + WS_BUCKET);

    // per-shard bucket capacity from available workspace (8-aligned for int4 reads);
    // capS == 0 -> all rows take the overflow-atomic path (slow but correct).
    int capS = 0;
    size_t avail = ws_size / sizeof(float);
    if (avail > (size_t)WS_BUCKET) {
        size_t per = (avail - (size_t)WS_BUCKET) / ((size_t)NEMB * NSH);
        if (per > 768) per = 768;
        capS = (int)per & ~7;
    }

    // zero cursors + esum (loss partials are fully overwritten by vq_main)
    hipMemsetAsync(ws + WS_CNT, 0, (size_t)(WS_LOSSP - WS_CNT) * sizeof(float), stream);

    vq_prep<<<65536 / 256, 256, 0, stream>>>(embed, ws + WS_ET);
    vq_e2<<<NEMB / 256, 256, 0, stream>>>(ws + WS_ET, ws + WS_E2);
    vq_prep_b<<<65536 / 256, 256, 0, stream>>>(embed, eh, el);
    vq_main<<<NROWS / 256, 256, 0, stream>>>(x, mask, eh, el, ws + WS_ET, ws + WS_E2,
                                             out, kwv, ws + WS_LOSSP);
    vq_bucket<<<NROWS / 256, 256, 0, stream>>>(kwv, x, cnt, bucket, ws + WS_ESUM, capS);
    vq_esum<<<NEMB, 512, 0, stream>>>(x, cnt, bucket, ws + WS_ESUM, capS);
    vq_finalA<<<1, 1024, 0, stream>>>(cluster_size, cnt, ws + WS_LOSSP,
                                      out, ws + WS_TOTAL);
    vq_finalB<<<65536 / 256, 256, 0, stream>>>(embed_avg, ws + WS_ESUM, out, ws + WS_TOTAL);
}